// Round 6
// baseline (864.572 us; speedup 1.0000x reference)
//
#include <hip/hip_runtime.h>
#include <hip/hip_bf16.h>

#define NN 10000
#define EE 160000
#define ET (EE + NN)   // 170000
#define TT 24
#define BB 8
#define FF 16
#define HH 64
#define OWW 12

// ---- workspace layout (element offsets, 4-byte elements) ----
#define O_DEG   0                    // float [NN]
#define O_CNT   (O_DEG + NN)         // int   [NN]
#define O_RSUM  (O_CNT + NN)         // float [TT*BB*HH]
#define O_DINV  (O_RSUM + TT*BB*HH)  // float [NN]
#define O_ROW   (O_DINV + NN)        // int   [NN+1]
#define O_CUR   (O_ROW + NN + 1)     // int   [NN]
#define O_CSRS  (O_CUR + NN)         // int   [ET]
#define O_CSRN  (O_CSRS + ET)        // float [ET]
#define O_GI    (O_CSRN + ET)        // float [TT*BB*3*HH]

// ---------------- degree + count ----------------
__global__ void k_deg(const int* __restrict__ ei, const float* __restrict__ ew,
                      float* __restrict__ deg, int* __restrict__ cnt) {
    int e = blockIdx.x * blockDim.x + threadIdx.x;
    if (e >= ET) return;
    int d; float w;
    if (e < EE) { d = ei[EE + e]; w = ew[e]; }
    else        { d = e - EE;     w = 1.f;   }
    atomicAdd(&deg[d], w);
    atomicAdd(&cnt[d], 1);
}

// ---------------- dinv ----------------
__global__ void k_dinv(const float* __restrict__ deg, float* __restrict__ dinv) {
    int i = blockIdx.x * blockDim.x + threadIdx.x;
    if (i >= NN) return;
    float dg = deg[i];
    dinv[i] = dg > 0.f ? rsqrtf(dg) : 0.f;
}

// ---------------- exclusive scan (single wave, chunked) ----------------
__global__ void k_scan_wave(const int* __restrict__ cnt, int* __restrict__ rowstart,
                            int* __restrict__ cursor) {
    int lane = threadIdx.x;                    // 0..63
    const int CH = (NN + 63) / 64;             // 157
    int lo = lane * CH;
    int hi = lo + CH; if (hi > NN) hi = NN;
    int s = 0;
    for (int i = lo; i < hi; i++) s += cnt[i];
    int x = s;
#pragma unroll
    for (int off = 1; off < 64; off <<= 1) {
        int y = __shfl_up(x, off);
        if (lane >= off) x += y;
    }
    int run = x - s;
    for (int i = lo; i < hi; i++) {
        rowstart[i] = run;
        cursor[i]   = run;
        run += cnt[i];
    }
    if (lane == 63) rowstart[NN] = x;
}

// ---------------- scatter edges into CSR (by dst) ----------------
__global__ void k_scatter(const int* __restrict__ ei, const float* __restrict__ ew,
                          const float* __restrict__ dinv, int* __restrict__ cursor,
                          int* __restrict__ csr_src, float* __restrict__ csr_norm) {
    int e = blockIdx.x * blockDim.x + threadIdx.x;
    if (e >= ET) return;
    int s, d; float w;
    if (e < EE) { s = ei[e]; d = ei[EE + e]; w = ew[e]; }
    else        { s = e - EE; d = s;         w = 1.f;   }
    float nrm = dinv[s] * w * dinv[d];
    int pos = atomicAdd(&cursor[d], 1);
    csr_src[pos]  = s;
    csr_norm[pos] = nrm;
}

// ---------------- heavy: per-(b,t) aggregate in F-space, matvec, relu, node-mean ----
// grid: (ceil(NN/256), B*T), block 256.  blockIdx.y = bt = b*T + t (x layout order).
__global__ __launch_bounds__(256)
void k_gcn(const float* __restrict__ x, const int* __restrict__ rowstart,
           const int* __restrict__ csr_src, const float* __restrict__ csr_norm,
           const float* __restrict__ W_gcn, const float* __restrict__ b_gcn,
           float* __restrict__ rnn_sum) {
    __shared__ __align__(16) float as[256][20];   // padded rows (80 B)
    __shared__ float part[4][64];
    const int bt = blockIdx.y;
    const float* xb = x + (size_t)bt * (NN * FF);
    int tid = threadIdx.x;
    int node = blockIdx.x * 256 + tid;
    float a[16];
#pragma unroll
    for (int f = 0; f < 16; f++) a[f] = 0.f;
    if (node < NN) {
        int rs = rowstart[node], re = rowstart[node + 1];
        for (int e = rs; e < re; e++) {
            int s = csr_src[e];
            float w = csr_norm[e];
            const float4* row = (const float4*)(xb + (size_t)s * 16);
            float4 r0 = row[0], r1 = row[1], r2 = row[2], r3 = row[3];
            a[0]  += w * r0.x; a[1]  += w * r0.y; a[2]  += w * r0.z; a[3]  += w * r0.w;
            a[4]  += w * r1.x; a[5]  += w * r1.y; a[6]  += w * r1.z; a[7]  += w * r1.w;
            a[8]  += w * r2.x; a[9]  += w * r2.y; a[10] += w * r2.z; a[11] += w * r2.w;
            a[12] += w * r3.x; a[13] += w * r3.y; a[14] += w * r3.z; a[15] += w * r3.w;
        }
    }
    {
        float4* asr = (float4*)&as[tid][0];
        asr[0] = make_float4(a[0],  a[1],  a[2],  a[3]);
        asr[1] = make_float4(a[4],  a[5],  a[6],  a[7]);
        asr[2] = make_float4(a[8],  a[9],  a[10], a[11]);
        asr[3] = make_float4(a[12], a[13], a[14], a[15]);
    }
    __syncthreads();
    int lane = tid & 63;
    int wid  = tid >> 6;
    float wc[16];
#pragma unroll
    for (int f = 0; f < 16; f++) wc[f] = W_gcn[f * HH + lane];
    float bg = b_gcn[lane];
    int base0 = wid * 64;
    int gbase = blockIdx.x * 256 + base0;
    int nvalid = NN - gbase;
    if (nvalid > 64) nvalid = 64;
    if (nvalid < 0)  nvalid = 0;
    float ysum = 0.f;
    for (int n = 0; n < nvalid; n++) {
        const float4* rr = (const float4*)&as[base0 + n][0];   // wave-uniform -> broadcast
        float4 v0 = rr[0], v1 = rr[1], v2 = rr[2], v3 = rr[3];
        float y = bg;
        y += v0.x * wc[0]  + v0.y * wc[1]  + v0.z * wc[2]  + v0.w * wc[3];
        y += v1.x * wc[4]  + v1.y * wc[5]  + v1.z * wc[6]  + v1.w * wc[7];
        y += v2.x * wc[8]  + v2.y * wc[9]  + v2.z * wc[10] + v2.w * wc[11];
        y += v3.x * wc[12] + v3.y * wc[13] + v3.z * wc[14] + v3.w * wc[15];
        ysum += fmaxf(y, 0.f);
    }
    part[wid][lane] = ysum;
    __syncthreads();
    if (wid == 0) {
        float s = part[0][lane] + part[1][lane] + part[2][lane] + part[3][lane];
        int b = bt / TT, t = bt % TT;
        atomicAdd(&rnn_sum[(t * BB + b) * HH + lane], s);
    }
}

// ---------------- gi = (rnn_sum/N) @ W_ih + b_ih for all t (parallel) ----------------
__global__ void k_gi(const float* __restrict__ rnn_sum, const float* __restrict__ W_ih,
                     const float* __restrict__ b_ih, float* __restrict__ gi_all) {
    __shared__ float xt[64];
    int g = blockIdx.x;
    int j = threadIdx.x;
    if (j < 64) xt[j] = rnn_sum[g * 64 + j] * (1.f / NN);
    __syncthreads();
    float acc = b_ih[j];
#pragma unroll
    for (int k = 0; k < 64; k++) acc += xt[k] * W_ih[k * 192 + j];
    gi_all[g * 192 + j] = acc;
}

// ---------------- fused GRU + attention + fc (single block, 512 thr) ----------------
__global__ __launch_bounds__(512)
void k_gru_attn(const float* __restrict__ gi_all, const float* __restrict__ W_hh,
                const float* __restrict__ b_hh, const float* __restrict__ W_attn,
                const float* __restrict__ b_attn, const float* __restrict__ v_w,
                const float* __restrict__ W_fc, const float* __restrict__ b_fc,
                float* __restrict__ out) {
    __shared__ float h_lds[BB][HH];
    __shared__ float gh_lds[BB][192];
    __shared__ float ro[TT][BB][HH];
    __shared__ float sc[BB][TT];
    __shared__ float aw[BB][TT];
    __shared__ float ctx[BB][HH];
    int tid = threadIdx.x;
    int lane = tid & 63, wid = tid >> 6;

    h_lds[wid][lane] = 0.f;
    __syncthreads();

    for (int t = 0; t < TT; t++) {
        for (int idx = tid; idx < BB * 192; idx += 512) {
            int b = idx / 192, j = idx % 192;
            float acc = b_hh[j];
            for (int k = 0; k < 64; k++) acc += h_lds[b][k] * W_hh[k * 192 + j];
            gh_lds[b][j] = acc;
        }
        __syncthreads();
        {
            int b = wid, h = lane;
            const float* gi = gi_all + (t * BB + b) * 192;
            float ir = gi[h], iz = gi[64 + h], inn = gi[128 + h];
            float hr = gh_lds[b][h], hz = gh_lds[b][64 + h], hn = gh_lds[b][128 + h];
            float r = 1.f / (1.f + expf(-(ir + hr)));
            float z = 1.f / (1.f + expf(-(iz + hz)));
            float n = tanhf(inn + r * hn);
            float hnew = (1.f - z) * n + z * h_lds[b][h];
            __syncthreads();
            h_lds[b][h] = hnew;
            ro[t][b][h] = hnew;
        }
        __syncthreads();
    }

    for (int bt = wid; bt < BB * TT; bt += 8) {
        int b = bt / TT, t = bt % TT;
        float e = b_attn[lane];
        for (int k = 0; k < 64; k++) e += h_lds[b][k] * W_attn[k * 64 + lane];
        for (int k = 0; k < 64; k++) e += ro[t][b][k] * W_attn[(64 + k) * 64 + lane];
        e = tanhf(e);
        float p = e * v_w[lane];
#pragma unroll
        for (int off = 32; off; off >>= 1) p += __shfl_xor(p, off);
        if (lane == 0) sc[b][t] = p;
    }
    __syncthreads();
    if (tid < 8) {
        float m = -1e30f;
        for (int t = 0; t < TT; t++) m = fmaxf(m, sc[tid][t]);
        float s = 0.f;
        for (int t = 0; t < TT; t++) { float v = expf(sc[tid][t] - m); aw[tid][t] = v; s += v; }
        float inv = 1.f / s;
        for (int t = 0; t < TT; t++) aw[tid][t] *= inv;
    }
    __syncthreads();
    {
        int b = wid, h = lane;
        float c = 0.f;
        for (int t = 0; t < TT; t++) c += aw[b][t] * ro[t][b][h];
        ctx[b][h] = c;
    }
    __syncthreads();
    // ---- outputs are FP32 (reference output dtype) ----
    if (tid < BB * OWW) {
        int b = tid / OWW, o = tid % OWW;
        float acc = b_fc[o];
        for (int k = 0; k < 64; k++) acc += h_lds[b][k] * W_fc[k * OWW + o];
        for (int k = 0; k < 64; k++) acc += ctx[b][k] * W_fc[(64 + k) * OWW + o];
        out[b * OWW + o] = acc;
    }
    if (tid < BB * TT) {
        int b = tid / TT, t = tid % TT;
        out[BB * OWW + b * TT + t] = aw[b][t];
    }
}

extern "C" void kernel_launch(void* const* d_in, const int* in_sizes, int n_in,
                              void* d_out, int out_size, void* d_ws, size_t ws_size,
                              hipStream_t stream) {
    const float* x      = (const float*)d_in[0];
    const int*   ei     = (const int*)d_in[1];
    const float* ew     = (const float*)d_in[2];
    const float* W_gcn  = (const float*)d_in[3];
    const float* b_gcn  = (const float*)d_in[4];
    const float* W_ih   = (const float*)d_in[5];
    const float* W_hh   = (const float*)d_in[6];
    const float* b_ih   = (const float*)d_in[7];
    const float* b_hh   = (const float*)d_in[8];
    const float* W_attn = (const float*)d_in[9];
    const float* b_attn = (const float*)d_in[10];
    const float* v_w    = (const float*)d_in[11];
    const float* W_fc   = (const float*)d_in[12];
    const float* b_fc   = (const float*)d_in[13];
    float* out = (float*)d_out;

    float* wsf = (float*)d_ws;
    float* deg      = wsf + O_DEG;
    int*   cnt      = (int*)(wsf + O_CNT);
    float* rsum     = wsf + O_RSUM;
    float* dinv     = wsf + O_DINV;
    int*   rowstart = (int*)(wsf + O_ROW);
    int*   cursor   = (int*)(wsf + O_CUR);
    int*   csr_src  = (int*)(wsf + O_CSRS);
    float* csr_norm = wsf + O_CSRN;
    float* gi_all   = wsf + O_GI;

    // zero deg, cnt, rnn_sum (contiguous at start of ws)
    hipMemsetAsync(wsf, 0, (size_t)(NN + NN + TT * BB * HH) * sizeof(float), stream);

    int eblocks = (ET + 255) / 256;
    k_deg<<<eblocks, 256, 0, stream>>>(ei, ew, deg, cnt);
    k_dinv<<<(NN + 255) / 256, 256, 0, stream>>>(deg, dinv);
    k_scan_wave<<<1, 64, 0, stream>>>(cnt, rowstart, cursor);
    k_scatter<<<eblocks, 256, 0, stream>>>(ei, ew, dinv, cursor, csr_src, csr_norm);
    k_gcn<<<dim3((NN + 255) / 256, BB * TT), 256, 0, stream>>>(
        x, rowstart, csr_src, csr_norm, W_gcn, b_gcn, rsum);
    k_gi<<<BB * TT, 192, 0, stream>>>(rsum, W_ih, b_ih, gi_all);
    k_gru_attn<<<1, 512, 0, stream>>>(gi_all, W_hh, b_hh, W_attn, b_attn, v_w,
                                      W_fc, b_fc, out);
}

// Round 7
// 666.446 us; speedup vs baseline: 1.2973x; 1.2973x over previous
//
#include <hip/hip_runtime.h>
#include <hip/hip_bf16.h>

#define NN 10000
#define EE 160000
#define ET (EE + NN)   // 170000
#define TT 24
#define BB 8
#define FF 16
#define HH 64
#define OWW 12
#define NBLK 40        // ceil(NN/256)

// ---- workspace layout (element offsets, 4-byte elements) ----
#define O_DEG   0                    // float [NN]
#define O_CNT   (O_DEG + NN)         // int   [NN]
#define O_RSUM  (O_CNT + NN)         // float [TT*BB*HH]
#define O_DINV  (O_RSUM + TT*BB*HH)  // float [NN]
#define O_ROW   (O_DINV + NN)        // int   [NN+1]
#define O_CUR   (O_ROW + NN + 1)     // int   [NN]
#define O_CSR   (O_CUR + NN)         // int2  [ET] (src, norm-bits)
#define O_GI    (O_CSR + 2*ET)       // float [TT*BB*3*HH]
#define O_RO    (O_GI + TT*BB*3*HH)  // float [TT*BB*HH]
#define O_HL    (O_RO + TT*BB*HH)    // float [BB*HH]
#define O_SC    (O_HL + BB*HH)       // float [BB*TT]

// ---------------- degree + count ----------------
__global__ void k_deg(const int* __restrict__ ei, const float* __restrict__ ew,
                      float* __restrict__ deg, int* __restrict__ cnt) {
    int e = blockIdx.x * blockDim.x + threadIdx.x;
    if (e >= ET) return;
    int d; float w;
    if (e < EE) { d = ei[EE + e]; w = ew[e]; }
    else        { d = e - EE;     w = 1.f;   }
    atomicAdd(&deg[d], w);
    atomicAdd(&cnt[d], 1);
}

// ---------------- dinv ----------------
__global__ void k_dinv(const float* __restrict__ deg, float* __restrict__ dinv) {
    int i = blockIdx.x * blockDim.x + threadIdx.x;
    if (i >= NN) return;
    float dg = deg[i];
    dinv[i] = dg > 0.f ? rsqrtf(dg) : 0.f;
}

// ---------------- exclusive scan (single wave, chunked) ----------------
__global__ void k_scan_wave(const int* __restrict__ cnt, int* __restrict__ rowstart,
                            int* __restrict__ cursor) {
    int lane = threadIdx.x;                    // 0..63
    const int CH = (NN + 63) / 64;             // 157
    int lo = lane * CH;
    int hi = lo + CH; if (hi > NN) hi = NN;
    int s = 0;
    for (int i = lo; i < hi; i++) s += cnt[i];
    int x = s;
#pragma unroll
    for (int off = 1; off < 64; off <<= 1) {
        int y = __shfl_up(x, off);
        if (lane >= off) x += y;
    }
    int run = x - s;
    for (int i = lo; i < hi; i++) {
        rowstart[i] = run;
        cursor[i]   = run;
        run += cnt[i];
    }
    if (lane == 63) rowstart[NN] = x;
}

// ---------------- scatter edges into CSR (by dst), packed int2 ----------------
__global__ void k_scatter(const int* __restrict__ ei, const float* __restrict__ ew,
                          const float* __restrict__ dinv, int* __restrict__ cursor,
                          int2* __restrict__ csr) {
    int e = blockIdx.x * blockDim.x + threadIdx.x;
    if (e >= ET) return;
    int s, d; float w;
    if (e < EE) { s = ei[e]; d = ei[EE + e]; w = ew[e]; }
    else        { s = e - EE; d = s;         w = 1.f;   }
    float nrm = dinv[s] * w * dinv[d];
    int pos = atomicAdd(&cursor[d], 1);
    csr[pos] = make_int2(s, __float_as_int(nrm));
}

// ---------------- heavy: XCD-swizzled, TM=2 bt-slices per block ----------------
// 1D grid 3840: xcd=id&7, q=id>>3, g=q/40, j=q%40, pair=g*8+xcd, bt={2p,2p+1}
__global__ __launch_bounds__(256)
void k_gcn(const float* __restrict__ x, const int* __restrict__ rowstart,
           const int2* __restrict__ csr, const float* __restrict__ W_gcn,
           const float* __restrict__ b_gcn, float* __restrict__ rnn_sum) {
    __shared__ __align__(16) float as[256][20];   // padded rows (80 B)
    __shared__ float part[4][64];
    int id = blockIdx.x;
    int xcd = id & 7;
    int q = id >> 3;
    int g = q / NBLK;
    int j = q % NBLK;
    int pair = g * 8 + xcd;             // 0..95
    int bt0 = pair * 2;
    const float* xb0 = x + (size_t)bt0 * (NN * FF);
    int tid = threadIdx.x;
    int node = j * 256 + tid;
    float a0[16], a1[16];
#pragma unroll
    for (int f = 0; f < 16; f++) { a0[f] = 0.f; a1[f] = 0.f; }
    if (node < NN) {
        int rs = rowstart[node], re = rowstart[node + 1];
        for (int e = rs; e < re; e++) {
            int2 ed = csr[e];
            int s = ed.x;
            float w = __int_as_float(ed.y);
            const float4* r0 = (const float4*)(xb0 + (size_t)s * 16);
            const float4* r1 = (const float4*)(xb0 + (size_t)(NN * FF) + (size_t)s * 16);
            float4 p0 = r0[0], p1 = r0[1], p2 = r0[2], p3 = r0[3];
            float4 q0 = r1[0], q1 = r1[1], q2 = r1[2], q3 = r1[3];
            a0[0]  += w * p0.x; a0[1]  += w * p0.y; a0[2]  += w * p0.z; a0[3]  += w * p0.w;
            a0[4]  += w * p1.x; a0[5]  += w * p1.y; a0[6]  += w * p1.z; a0[7]  += w * p1.w;
            a0[8]  += w * p2.x; a0[9]  += w * p2.y; a0[10] += w * p2.z; a0[11] += w * p2.w;
            a0[12] += w * p3.x; a0[13] += w * p3.y; a0[14] += w * p3.z; a0[15] += w * p3.w;
            a1[0]  += w * q0.x; a1[1]  += w * q0.y; a1[2]  += w * q0.z; a1[3]  += w * q0.w;
            a1[4]  += w * q1.x; a1[5]  += w * q1.y; a1[6]  += w * q1.z; a1[7]  += w * q1.w;
            a1[8]  += w * q2.x; a1[9]  += w * q2.y; a1[10] += w * q2.z; a1[11] += w * q2.w;
            a1[12] += w * q3.x; a1[13] += w * q3.y; a1[14] += w * q3.z; a1[15] += w * q3.w;
        }
    }
    int lane = tid & 63;
    int wid  = tid >> 6;
    float wc[16];
#pragma unroll
    for (int f = 0; f < 16; f++) wc[f] = W_gcn[f * HH + lane];
    float bg = b_gcn[lane];
    int base0 = wid * 64;
    int gbase = j * 256 + base0;
    int nvalid = NN - gbase;
    if (nvalid > 64) nvalid = 64;
    if (nvalid < 0)  nvalid = 0;

#pragma unroll
    for (int pp = 0; pp < 2; pp++) {
        const float* av = pp ? a1 : a0;
        {
            float4* asr = (float4*)&as[tid][0];
            asr[0] = make_float4(av[0],  av[1],  av[2],  av[3]);
            asr[1] = make_float4(av[4],  av[5],  av[6],  av[7]);
            asr[2] = make_float4(av[8],  av[9],  av[10], av[11]);
            asr[3] = make_float4(av[12], av[13], av[14], av[15]);
        }
        __syncthreads();
        float ysum = 0.f;
        for (int n = 0; n < nvalid; n++) {
            const float4* rr = (const float4*)&as[base0 + n][0];   // wave-uniform broadcast
            float4 v0 = rr[0], v1 = rr[1], v2 = rr[2], v3 = rr[3];
            float y = bg;
            y += v0.x * wc[0]  + v0.y * wc[1]  + v0.z * wc[2]  + v0.w * wc[3];
            y += v1.x * wc[4]  + v1.y * wc[5]  + v1.z * wc[6]  + v1.w * wc[7];
            y += v2.x * wc[8]  + v2.y * wc[9]  + v2.z * wc[10] + v2.w * wc[11];
            y += v3.x * wc[12] + v3.y * wc[13] + v3.z * wc[14] + v3.w * wc[15];
            ysum += fmaxf(y, 0.f);
        }
        part[wid][lane] = ysum;
        __syncthreads();
        if (wid == 0) {
            float s = part[0][lane] + part[1][lane] + part[2][lane] + part[3][lane];
            int bt = bt0 + pp;
            int b = bt / TT, t = bt % TT;
            atomicAdd(&rnn_sum[(t * BB + b) * HH + lane], s);
        }
        __syncthreads();   // protect part[] and as[] before next pass
    }
}

// ---------------- gi = (rnn_sum/N) @ W_ih + b_ih for all t (parallel) ----------------
__global__ void k_gi(const float* __restrict__ rnn_sum, const float* __restrict__ W_ih,
                     const float* __restrict__ b_ih, float* __restrict__ gi_all) {
    __shared__ float xt[64];
    int g = blockIdx.x;
    int j = threadIdx.x;
    if (j < 64) xt[j] = rnn_sum[g * 64 + j] * (1.f / NN);
    __syncthreads();
    float acc = b_ih[j];
#pragma unroll
    for (int k = 0; k < 64; k++) acc += xt[k] * W_ih[k * 192 + j];
    gi_all[g * 192 + j] = acc;
}

// ---------------- GRU only: single block 256 thr, W_hh in registers ----------------
__global__ __launch_bounds__(256)
void k_gru(const float* __restrict__ gi_all, const float* __restrict__ W_hh,
           const float* __restrict__ b_hh, float* __restrict__ ro_g,
           float* __restrict__ hlast_g) {
    __shared__ float h_lds[BB][HH];       // 2 KB
    __shared__ float gh_lds[BB][192];     // 6 KB
    int tid = threadIdx.x;

    float wreg[64];
    float bh = 0.f;
    if (tid < 192) {
#pragma unroll
        for (int k = 0; k < 64; k++) wreg[k] = W_hh[k * 192 + tid];
        bh = b_hh[tid];
    }
    h_lds[tid >> 6][tid & 63] = 0.f;
    h_lds[(tid + 256) >> 6][tid & 63] = 0.f;
    __syncthreads();

    for (int t = 0; t < TT; t++) {
        if (tid < 192) {
#pragma unroll
            for (int b = 0; b < BB; b++) {
                const float4* h4 = (const float4*)&h_lds[b][0];
                float acc = bh;
#pragma unroll
                for (int k4 = 0; k4 < 16; k4++) {
                    float4 hv = h4[k4];
                    acc += hv.x * wreg[4 * k4 + 0];
                    acc += hv.y * wreg[4 * k4 + 1];
                    acc += hv.z * wreg[4 * k4 + 2];
                    acc += hv.w * wreg[4 * k4 + 3];
                }
                gh_lds[b][tid] = acc;
            }
        }
        __syncthreads();
#pragma unroll
        for (int it = 0; it < 2; it++) {
            int idx = tid + it * 256;
            int b = idx >> 6, h = idx & 63;
            const float* gi = gi_all + (t * BB + b) * 192;
            float ir = gi[h], iz = gi[64 + h], inn = gi[128 + h];
            float hr = gh_lds[b][h], hz = gh_lds[b][64 + h], hn = gh_lds[b][128 + h];
            float r = 1.f / (1.f + expf(-(ir + hr)));
            float z = 1.f / (1.f + expf(-(iz + hz)));
            float n = tanhf(inn + r * hn);
            float hnew = (1.f - z) * n + z * h_lds[b][h];
            h_lds[b][h] = hnew;
            ro_g[(t * BB + b) * HH + h] = hnew;
        }
        __syncthreads();
    }
    {
        int idx = tid;
        hlast_g[idx] = h_lds[idx >> 6][idx & 63];
        idx = tid + 256;
        hlast_g[idx] = h_lds[idx >> 6][idx & 63];
    }
}

// ---------------- attention scores: 192 blocks (one per b,t), 64 thr ----------------
__global__ __launch_bounds__(64)
void k_attn(const float* __restrict__ ro_g, const float* __restrict__ hlast_g,
            const float* __restrict__ W_attn, const float* __restrict__ b_attn,
            const float* __restrict__ v_w, float* __restrict__ sc_g) {
    int bt = blockIdx.x;          // b*TT + t
    int b = bt / TT, t = bt % TT;
    int lane = threadIdx.x;
    float e = b_attn[lane];
    const float* hl = hlast_g + b * HH;
    const float* ro = ro_g + (t * BB + b) * HH;
    for (int k = 0; k < 64; k++) e += hl[k] * W_attn[k * 64 + lane];
    for (int k = 0; k < 64; k++) e += ro[k] * W_attn[(64 + k) * 64 + lane];
    e = tanhf(e);
    float p = e * v_w[lane];
#pragma unroll
    for (int off = 32; off; off >>= 1) p += __shfl_xor(p, off);
    if (lane == 0) sc_g[bt] = p;
}

// ---------------- final: softmax, context, fc (8 blocks, 64 thr) ----------------
__global__ __launch_bounds__(64)
void k_final(const float* __restrict__ sc_g, const float* __restrict__ ro_g,
             const float* __restrict__ hlast_g, const float* __restrict__ W_fc,
             const float* __restrict__ b_fc, float* __restrict__ out) {
    __shared__ float aw_lds[TT];
    __shared__ float ctx_lds[HH];
    int b = blockIdx.x;
    int lane = threadIdx.x;
    float s = (lane < TT) ? sc_g[b * TT + lane] : -1e30f;
    float m = s;
#pragma unroll
    for (int off = 32; off; off >>= 1) m = fmaxf(m, __shfl_xor(m, off));
    float ev = (lane < TT) ? expf(s - m) : 0.f;
    float tot = ev;
#pragma unroll
    for (int off = 32; off; off >>= 1) tot += __shfl_xor(tot, off);
    float awn = ev / tot;
    if (lane < TT) {
        aw_lds[lane] = awn;
        out[BB * OWW + b * TT + lane] = awn;
    }
    __syncthreads();
    float c = 0.f;
    for (int t = 0; t < TT; t++) c += aw_lds[t] * ro_g[(t * BB + b) * HH + lane];
    ctx_lds[lane] = c;
    __syncthreads();
    if (lane < OWW) {
        const float* hl = hlast_g + b * HH;
        float acc = b_fc[lane];
        for (int k = 0; k < 64; k++) acc += hl[k] * W_fc[k * OWW + lane];
        for (int k = 0; k < 64; k++) acc += ctx_lds[k] * W_fc[(64 + k) * OWW + lane];
        out[b * OWW + lane] = acc;
    }
}

extern "C" void kernel_launch(void* const* d_in, const int* in_sizes, int n_in,
                              void* d_out, int out_size, void* d_ws, size_t ws_size,
                              hipStream_t stream) {
    const float* x      = (const float*)d_in[0];
    const int*   ei     = (const int*)d_in[1];
    const float* ew     = (const float*)d_in[2];
    const float* W_gcn  = (const float*)d_in[3];
    const float* b_gcn  = (const float*)d_in[4];
    const float* W_ih   = (const float*)d_in[5];
    const float* W_hh   = (const float*)d_in[6];
    const float* b_ih   = (const float*)d_in[7];
    const float* b_hh   = (const float*)d_in[8];
    const float* W_attn = (const float*)d_in[9];
    const float* b_attn = (const float*)d_in[10];
    const float* v_w    = (const float*)d_in[11];
    const float* W_fc   = (const float*)d_in[12];
    const float* b_fc   = (const float*)d_in[13];
    float* out = (float*)d_out;

    float* wsf = (float*)d_ws;
    float* deg      = wsf + O_DEG;
    int*   cnt      = (int*)(wsf + O_CNT);
    float* rsum     = wsf + O_RSUM;
    float* dinv     = wsf + O_DINV;
    int*   rowstart = (int*)(wsf + O_ROW);
    int*   cursor   = (int*)(wsf + O_CUR);
    int2*  csr      = (int2*)(wsf + O_CSR);
    float* gi_all   = wsf + O_GI;
    float* ro_g     = wsf + O_RO;
    float* hlast_g  = wsf + O_HL;
    float* sc_g     = wsf + O_SC;

    // zero deg, cnt, rnn_sum (contiguous at start of ws)
    hipMemsetAsync(wsf, 0, (size_t)(NN + NN + TT * BB * HH) * sizeof(float), stream);

    int eblocks = (ET + 255) / 256;
    k_deg<<<eblocks, 256, 0, stream>>>(ei, ew, deg, cnt);
    k_dinv<<<(NN + 255) / 256, 256, 0, stream>>>(deg, dinv);
    k_scan_wave<<<1, 64, 0, stream>>>(cnt, rowstart, cursor);
    k_scatter<<<eblocks, 256, 0, stream>>>(ei, ew, dinv, cursor, csr);
    k_gcn<<<8 * (96 / 8) * NBLK, 256, 0, stream>>>(   // 3840 blocks
        x, rowstart, csr, W_gcn, b_gcn, rsum);
    k_gi<<<TT * BB, 192, 0, stream>>>(rsum, W_ih, b_ih, gi_all);
    k_gru<<<1, 256, 0, stream>>>(gi_all, W_hh, b_hh, ro_g, hlast_g);
    k_attn<<<BB * TT, 64, 0, stream>>>(ro_g, hlast_g, W_attn, b_attn, v_w, sc_g);
    k_final<<<BB, 64, 0, stream>>>(sc_g, ro_g, hlast_g, W_fc, b_fc, out);
}